// Round 13
// baseline (84.667 us; speedup 1.0000x reference)
//
#include <hip/hip_runtime.h>

constexpr int BB = 8, CC = 512, TT = 8192;
constexpr float MOM = 0.05f, EPSV = 1e-6f;

typedef float v4f __attribute__((ext_vector_type(4)));

__device__ __forceinline__ void wave_incl_affine(float& A, float& B) {
  const int lane = threadIdx.x & 63;
  #pragma unroll
  for (int off = 1; off < 64; off <<= 1) {
    float pA = __shfl_up(A, off, 64);
    float pB = __shfl_up(B, off, 64);
    if (lane >= off) { B = fmaf(A, pB, B); A *= pA; }
  }
}

// block-wide exclusive affine prefix applied to y0 = 0 (512 thr = 8 waves)
__device__ __forceinline__ float block_scan_prev(float A, float B,
                                                 float* wAs, float* wBs) {
  const int lane = threadIdx.x & 63, wid = threadIdx.x >> 6;
  wave_incl_affine(A, B);
  __syncthreads();
  if (lane == 63) { wAs[wid] = A; wBs[wid] = B; }
  __syncthreads();
  float cB = 0.f;
  for (int w = 0; w < wid; ++w) cB = fmaf(wAs[w], cB, wBs[w]);
  float leA = __shfl_up(A, 1, 64);
  float leB = __shfl_up(B, 1, 64);
  if (lane == 0) { leA = 1.f; leB = 0.f; }
  return fmaf(leA, cB, leB);
}

// K1: per (b,t) weighted reductions over C -> sa, sb, sb2. (unchanged, R11)
__global__ __launch_bounds__(512) void k_reduce(
    const float* __restrict__ x, const float* __restrict__ Wa,
    const float* __restrict__ Wb, float* __restrict__ sa,
    float* __restrict__ sb, float* __restrict__ sb2) {
  __shared__ float lwa[CC], lwb[CC];
  __shared__ float red[3][8][256];
  __shared__ float xw[32];

  const int tid = threadIdx.x;
  const int lane = tid & 63;
  const int wid = tid >> 6;
  const int b = blockIdx.x >> 5;           // 32 t-tiles per batch
  const int t0 = (blockIdx.x & 31) * 256;

  // softmax over C for Wa, Wb (redundant per block)
  {
    float va = Wa[tid], vb = Wb[tid];
    float ma = va, mb = vb;
    #pragma unroll
    for (int off = 32; off > 0; off >>= 1) {
      ma = fmaxf(ma, __shfl_down(ma, off, 64));
      mb = fmaxf(mb, __shfl_down(mb, off, 64));
    }
    if (lane == 0) { xw[wid] = ma; xw[8 + wid] = mb; }
    __syncthreads();
    ma = xw[0]; mb = xw[8];
    #pragma unroll
    for (int w = 1; w < 8; ++w) { ma = fmaxf(ma, xw[w]); mb = fmaxf(mb, xw[8 + w]); }
    const float ea = expf(va - ma), eb = expf(vb - mb);
    float sA = ea, sB = eb;
    #pragma unroll
    for (int off = 32; off > 0; off >>= 1) {
      sA += __shfl_down(sA, off, 64);
      sB += __shfl_down(sB, off, 64);
    }
    if (lane == 0) { xw[16 + wid] = sA; xw[24 + wid] = sB; }
    __syncthreads();
    sA = xw[16]; sB = xw[24];
    #pragma unroll
    for (int w = 1; w < 8; ++w) { sA += xw[16 + w]; sB += xw[24 + w]; }
    lwa[tid] = ea * (1.f / sA);
    lwb[tid] = eb * (1.f / sB);
  }
  __syncthreads();

  const int t4 = lane * 4;
  const int cbase = wid * 64;
  const float* xp = x + ((size_t)(b * CC + cbase)) * TT + t0 + t4;
  float a0=0,a1=0,a2=0,a3=0, b0=0,b1=0,b2=0,b3=0, q0=0,q1=0,q2=0,q3=0;
  #pragma unroll 8
  for (int cc = 0; cc < 64; ++cc) {
    float4 xv = *(const float4*)(xp + (size_t)cc * TT);
    const float wac = lwa[cbase + cc], wbc = lwb[cbase + cc];
    a0 = fmaf(wac, xv.x, a0); a1 = fmaf(wac, xv.y, a1);
    a2 = fmaf(wac, xv.z, a2); a3 = fmaf(wac, xv.w, a3);
    b0 = fmaf(wbc, xv.x, b0); b1 = fmaf(wbc, xv.y, b1);
    b2 = fmaf(wbc, xv.z, b2); b3 = fmaf(wbc, xv.w, b3);
    q0 = fmaf(wbc * xv.x, xv.x, q0); q1 = fmaf(wbc * xv.y, xv.y, q1);
    q2 = fmaf(wbc * xv.z, xv.z, q2); q3 = fmaf(wbc * xv.w, xv.w, q3);
  }
  red[0][wid][t4+0]=a0; red[0][wid][t4+1]=a1; red[0][wid][t4+2]=a2; red[0][wid][t4+3]=a3;
  red[1][wid][t4+0]=b0; red[1][wid][t4+1]=b1; red[1][wid][t4+2]=b2; red[1][wid][t4+3]=b3;
  red[2][wid][t4+0]=q0; red[2][wid][t4+1]=q1; red[2][wid][t4+2]=q2; red[2][wid][t4+3]=q3;
  __syncthreads();

  if (tid < 64) {
    const int o = tid * 4;
    float oa[4] = {0,0,0,0}, ob[4] = {0,0,0,0}, oq[4] = {0,0,0,0};
    #pragma unroll
    for (int w = 0; w < 8; ++w) {
      #pragma unroll
      for (int k = 0; k < 4; ++k) {
        oa[k] += red[0][w][o+k];
        ob[k] += red[1][w][o+k];
        oq[k] += red[2][w][o+k];
      }
    }
    const size_t dst = (size_t)b * TT + t0 + o;
    *(float4*)(sa  + dst) = make_float4(oa[0], oa[1], oa[2], oa[3]);
    *(float4*)(sb  + dst) = make_float4(ob[0], ob[1], ob[2], ob[3]);
    *(float4*)(sb2 + dst) = make_float4(oq[0], oq[1], oq[2], oq[3]);
  }
}

// K2: scan + normalize. Each block REDUNDANTLY recomputes the full-T dual
// EMA scan for its batch (~4 us, stats are L2/L3-resident; no cross-block
// sync of any kind), keeps its 256-t slice of mean/inv in LDS, then streams
// the normalize for its (b, c-half, t-tile).
__global__ __launch_bounds__(512) void k_scan_out(
    const float* __restrict__ x, const float* __restrict__ g,
    const float* __restrict__ sa, const float* __restrict__ sb,
    const float* __restrict__ sb2, const float* __restrict__ wo,
    const float* __restrict__ bo, float* __restrict__ out) {
  __shared__ float wAs[8], wBs[8];
  __shared__ float mean_s[256], inv_s[256];

  const int tid = threadIdx.x;
  const int lane = tid & 63;
  const int wid = tid >> 6;
  const int tt = blockIdx.x & 31;
  const int ch = (blockIdx.x >> 5) & 1;
  const int b  = blockIdx.x >> 6;
  const int t0 = tt * 256;

  // ---- prologue: full-T dual EMA scan (CH=16 per thread) ----
  constexpr int CH = 16;
  const size_t sbase = (size_t)b * TT + (size_t)tid * CH;
  float gt[CH], pa[CH], mv[CH];

  float A = 1.f, Bv = 0.f;
  #pragma unroll
  for (int j = 0; j < CH; j += 4) {
    const v4f gq = *(const v4f*)(g  + sbase + j);
    const v4f aq = *(const v4f*)(sa + sbase + j);
    #pragma unroll
    for (int k = 0; k < 4; ++k) {
      const float gg = gq[k] * MOM;
      gt[j + k] = gg;
      const float p = gg * aq[k];
      pa[j + k] = p;
      const float a = 1.f - gg;
      A *= a;
      Bv = fmaf(a, Bv, p);
    }
  }
  float m = block_scan_prev(A, Bv, wAs, wBs);

  float A2 = 1.f, B2 = 0.f;
  #pragma unroll
  for (int j = 0; j < CH; j += 4) {
    const v4f bq = *(const v4f*)(sb  + sbase + j);
    const v4f qq = *(const v4f*)(sb2 + sbase + j);
    #pragma unroll
    for (int k = 0; k < 4; ++k) {
      const float a = 1.f - gt[j + k];
      m = fmaf(a, m, pa[j + k]);
      mv[j + k] = m;
      const float vi = fmaf(m, m, fmaf(-2.f * m, bq[k], qq[k]));  // sum(wb)=1
      const float pv = gt[j + k] * vi;
      pa[j + k] = pv;
      A2 *= a;
      B2 = fmaf(a, B2, pv);
    }
  }
  float v = block_scan_prev(A2, B2, wAs, wBs);

  // stash this block's 256-t slice of mean/inv into LDS
  const int town = tid - tt * 16;          // owner threads: [tt*16, tt*16+16)
  if (town >= 0 && town < 16) {
    const int o = town * CH;
    #pragma unroll
    for (int j = 0; j < CH; ++j) mean_s[o + j] = mv[j];
  }
  // every thread must replay its var chain regardless (v is thread-local)
  float iv[CH];
  #pragma unroll
  for (int j = 0; j < CH; ++j) {
    v = fmaf(1.f - gt[j], v, pa[j]);
    iv[j] = rsqrtf(v + EPSV);
  }
  if (town >= 0 && town < 16) {
    const int o = town * CH;
    #pragma unroll
    for (int j = 0; j < CH; ++j) inv_s[o + j] = iv[j];
  }
  __syncthreads();

  // ---- normalize: lane owns one t-quad, loops 32 channels at stride TT ----
  const int t4 = lane * 4;
  const int cbase = ch * 256 + wid * 32;
  const v4f m4 = *(const v4f*)&mean_s[t4];
  const v4f i4 = *(const v4f*)&inv_s[t4];

  const size_t off0 = ((size_t)(b * CC + cbase)) * TT + t0 + t4;
  const float* xp = x + off0;
  float* op = out + off0;

  #pragma unroll 8
  for (int cc = 0; cc < 32; ++cc) {
    const int c = cbase + cc;
    const v4f xv = *(const v4f*)(xp + (size_t)cc * TT);
    const v4f o = (xv - m4) * i4 * wo[c] + bo[c];
    __builtin_nontemporal_store(o, (v4f*)(op + (size_t)cc * TT));
  }
}

extern "C" void kernel_launch(void* const* d_in, const int* in_sizes, int n_in,
                              void* d_out, int out_size, void* d_ws, size_t ws_size,
                              hipStream_t stream) {
  const float* x  = (const float*)d_in[0];  // (B, C, T)
  const float* g  = (const float*)d_in[1];  // (B, 1, T)
  const float* Wa = (const float*)d_in[2];  // (1, C, 1)
  const float* Wb = (const float*)d_in[3];  // (1, C, 1)
  const float* Wo = (const float*)d_in[4];  // (C, 1, 1)
  const float* Bo = (const float*)d_in[5];  // (C,)
  float* out = (float*)d_out;

  constexpr int BT = BB * TT;
  float* ws  = (float*)d_ws;
  float* sa  = ws;                // B*T
  float* sb  = sa + BT;
  float* sb2 = sb + BT;           // total 768 KiB

  k_reduce<<<BB * 32, 512, 0, stream>>>(x, Wa, Wb, sa, sb, sb2);
  k_scan_out<<<BB * 2 * 32, 512, 0, stream>>>(x, g, sa, sb, sb2, Wo, Bo, out);
}

// Round 14
// 83.773 us; speedup vs baseline: 1.0107x; 1.0107x over previous
//
#include <hip/hip_runtime.h>

constexpr int BB = 8, CC = 512, TT = 8192;
static_assert((TT & (TT - 1)) == 0 && (CC & (CC - 1)) == 0, "pow2");
constexpr int LOG_T = 13, LOG_C = 9;
constexpr float MOM = 0.05f, EPSV = 1e-6f;

typedef float v4f __attribute__((ext_vector_type(4)));

// ------- kernel 1: inline softmax + per (b,t) weighted reductions over C ----
// 512 threads = 8 waves; wave wid covers channels [wid*64, wid*64+64).
// lane l covers t = tbase + 4*l .. +3 (float4). 1 KiB/wave/channel, coalesced.
__global__ __launch_bounds__(512) void k_reduce_c(const float* __restrict__ x,
                                                  const float* __restrict__ Wa,
                                                  const float* __restrict__ Wb,
                                                  float* __restrict__ sa,
                                                  float* __restrict__ sb,
                                                  float* __restrict__ sb2) {
  __shared__ float lwa[CC];
  __shared__ float lwb[CC];
  __shared__ float xw[32];
  __shared__ float red[3][8][256];
  const int tid = threadIdx.x;
  const int lane = tid & 63;
  const int wid = tid >> 6;

  // --- softmax over C for Wa and Wb (one element per thread) ---
  float va = Wa[tid], vb = Wb[tid];
  float ma = va, mb = vb;
  #pragma unroll
  for (int off = 32; off > 0; off >>= 1) {
    ma = fmaxf(ma, __shfl_down(ma, off, 64));
    mb = fmaxf(mb, __shfl_down(mb, off, 64));
  }
  if (lane == 0) { xw[wid] = ma; xw[8 + wid] = mb; }
  __syncthreads();
  ma = xw[0]; mb = xw[8];
  #pragma unroll
  for (int w = 1; w < 8; ++w) { ma = fmaxf(ma, xw[w]); mb = fmaxf(mb, xw[8 + w]); }
  float ea = expf(va - ma), eb = expf(vb - mb);
  float sA = ea, sB = eb;
  #pragma unroll
  for (int off = 32; off > 0; off >>= 1) {
    sA += __shfl_down(sA, off, 64);
    sB += __shfl_down(sB, off, 64);
  }
  if (lane == 0) { xw[16 + wid] = sA; xw[24 + wid] = sB; }
  __syncthreads();
  sA = xw[16]; sB = xw[24];
  #pragma unroll
  for (int w = 1; w < 8; ++w) { sA += xw[16 + w]; sB += xw[24 + w]; }
  lwa[tid] = ea * (1.f / sA);
  lwb[tid] = eb * (1.f / sB);
  __syncthreads();

  // --- main weighted reduction over C ---
  const int tilesPerB = TT / 256;  // 32
  const int b = blockIdx.x / tilesPerB;
  const int tbase = (blockIdx.x % tilesPerB) * 256;
  const int t = tbase + lane * 4;
  const int cbase = wid * 64;
  const float* xp = x + ((size_t)(b * CC + cbase)) * TT + t;

  float a0=0,a1=0,a2=0,a3=0;
  float b0=0,b1=0,b2=0,b3=0;
  float q0=0,q1=0,q2=0,q3=0;
  #pragma unroll 8
  for (int cc = 0; cc < 64; ++cc) {
    float4 xv = *(const float4*)(xp + (size_t)cc * TT);
    float wac = lwa[cbase + cc];
    float wbc = lwb[cbase + cc];
    a0 = fmaf(wac, xv.x, a0); a1 = fmaf(wac, xv.y, a1);
    a2 = fmaf(wac, xv.z, a2); a3 = fmaf(wac, xv.w, a3);
    b0 = fmaf(wbc, xv.x, b0); b1 = fmaf(wbc, xv.y, b1);
    b2 = fmaf(wbc, xv.z, b2); b3 = fmaf(wbc, xv.w, b3);
    q0 = fmaf(wbc * xv.x, xv.x, q0); q1 = fmaf(wbc * xv.y, xv.y, q1);
    q2 = fmaf(wbc * xv.z, xv.z, q2); q3 = fmaf(wbc * xv.w, xv.w, q3);
  }
  const int li = lane * 4;
  red[0][wid][li+0]=a0; red[0][wid][li+1]=a1; red[0][wid][li+2]=a2; red[0][wid][li+3]=a3;
  red[1][wid][li+0]=b0; red[1][wid][li+1]=b1; red[1][wid][li+2]=b2; red[1][wid][li+3]=b3;
  red[2][wid][li+0]=q0; red[2][wid][li+1]=q1; red[2][wid][li+2]=q2; red[2][wid][li+3]=q3;
  __syncthreads();

  if (tid < 64) {
    const int o = tid * 4;
    float oa[4] = {0,0,0,0}, ob[4] = {0,0,0,0}, oq[4] = {0,0,0,0};
    #pragma unroll
    for (int w = 0; w < 8; ++w) {
      #pragma unroll
      for (int k = 0; k < 4; ++k) {
        oa[k] += red[0][w][o+k];
        ob[k] += red[1][w][o+k];
        oq[k] += red[2][w][o+k];
      }
    }
    const size_t dst = (size_t)b * TT + tbase + o;
    *(float4*)(sa  + dst) = make_float4(oa[0], oa[1], oa[2], oa[3]);
    *(float4*)(sb  + dst) = make_float4(ob[0], ob[1], ob[2], ob[3]);
    *(float4*)(sb2 + dst) = make_float4(oq[0], oq[1], oq[2], oq[3]);
  }
}

// ---------------- kernel 2: per-batch gated-EMA scans over T ----------------
__device__ __forceinline__ float affine_scan_prev(float A, float B, int tid,
                                                  float* wAs, float* wBs) {
  const int lane = tid & 63;
  const int wid = tid >> 6;
  #pragma unroll
  for (int off = 1; off < 64; off <<= 1) {
    float pA = __shfl_up(A, off, 64);
    float pB = __shfl_up(B, off, 64);
    if (lane >= off) { B = fmaf(A, pB, B); A *= pA; }
  }
  __syncthreads();  // protect scratch from previous call
  if (lane == 63) { wAs[wid] = A; wBs[wid] = B; }
  __syncthreads();
  float cB = 0.f;
  for (int w = 0; w < wid; ++w) cB = fmaf(wAs[w], cB, wBs[w]);
  float leA = __shfl_up(A, 1, 64);
  float leB = __shfl_up(B, 1, 64);
  if (lane == 0) { leA = 1.f; leB = 0.f; }
  return fmaf(leA, cB, leB);  // prefix applied to y0 = 0
}

__global__ __launch_bounds__(1024) void k_scan(const float* __restrict__ g,
                                               const float* __restrict__ sa,
                                               const float* __restrict__ sb,
                                               const float* __restrict__ sb2,
                                               float* __restrict__ mean,
                                               float* __restrict__ inv) {
  constexpr int CH = 8;  // 1024 threads * 8 = 8192
  __shared__ float wAs[16], wBs[16];
  const int tid = threadIdx.x;
  const size_t base = (size_t)blockIdx.x * TT + (size_t)tid * CH;

  float gv[CH], av[CH], bv[CH], qv[CH];
  *(float4*)(gv)     = *(const float4*)(g   + base);
  *(float4*)(gv + 4) = *(const float4*)(g   + base + 4);
  *(float4*)(av)     = *(const float4*)(sa  + base);
  *(float4*)(av + 4) = *(const float4*)(sa  + base + 4);
  *(float4*)(bv)     = *(const float4*)(sb  + base);
  *(float4*)(bv + 4) = *(const float4*)(sb  + base + 4);
  *(float4*)(qv)     = *(const float4*)(sb2 + base);
  *(float4*)(qv + 4) = *(const float4*)(sb2 + base + 4);

  float gt[CH], pa[CH];
  float A = 1.f, Bv = 0.f;
  #pragma unroll
  for (int j = 0; j < CH; ++j) {
    float gg = gv[j] * MOM;
    gt[j] = gg;
    float p = gg * av[j];
    pa[j] = p;
    float a = 1.f - gg;
    A *= a;
    Bv = fmaf(a, Bv, p);
  }
  float m = affine_scan_prev(A, Bv, tid, wAs, wBs);

  float m4[CH];
  float A2 = 1.f, B2 = 0.f;
  #pragma unroll
  for (int j = 0; j < CH; ++j) {
    float a = 1.f - gt[j];
    m = fmaf(a, m, pa[j]);
    m4[j] = m;
    float vi = fmaf(m, m, fmaf(-2.f * m, bv[j], qv[j]));  // sum(wb)=1
    float pv = gt[j] * vi;
    pa[j] = pv;
    A2 *= a;
    B2 = fmaf(a, B2, pv);
  }
  *(float4*)(mean + base)     = *(float4*)(m4);
  *(float4*)(mean + base + 4) = *(float4*)(m4 + 4);

  float v = affine_scan_prev(A2, B2, tid, wAs, wBs);

  float i4[CH];
  #pragma unroll
  for (int j = 0; j < CH; ++j) {
    v = fmaf(1.f - gt[j], v, pa[j]);
    i4[j] = rsqrtf(v + EPSV);
  }
  *(float4*)(inv + base)     = *(float4*)(i4);
  *(float4*)(inv + base + 4) = *(float4*)(i4 + 4);
}

// ---------------- kernel 3: pointwise output (flat, PLAIN stores) ----------
// 8192 blocks x 256 threads x 4 float4 each == exactly B*C*T floats.
// Isolated A/B vs R3-best: __builtin_nontemporal_store removed.
__global__ __launch_bounds__(256) void k_out(const float* __restrict__ x,
                                             const float* __restrict__ mean,
                                             const float* __restrict__ inv,
                                             const float* __restrict__ wo,
                                             const float* __restrict__ bo,
                                             float* __restrict__ out) {
  const size_t base4 = (size_t)blockIdx.x * 1024 + threadIdx.x;
  #pragma unroll
  for (int j = 0; j < 4; ++j) {
    const size_t idx = base4 + (size_t)j * 256;
    const size_t flat = idx * 4;
    const int t = (int)(flat & (TT - 1));
    const size_t rem = flat >> LOG_T;
    const int c = (int)(rem & (CC - 1));
    const int b = (int)(rem >> LOG_C);
    float4 xv = *(const float4*)(x + flat);
    const size_t mi = ((size_t)b << LOG_T) + t;
    float4 m4 = *(const float4*)(mean + mi);
    float4 i4 = *(const float4*)(inv + mi);
    const float w = wo[c], bb = bo[c];
    v4f o;
    o.x = fmaf((xv.x - m4.x) * i4.x, w, bb);
    o.y = fmaf((xv.y - m4.y) * i4.y, w, bb);
    o.z = fmaf((xv.z - m4.z) * i4.z, w, bb);
    o.w = fmaf((xv.w - m4.w) * i4.w, w, bb);
    *(v4f*)(out + flat) = o;   // plain store (A/B vs nt)
  }
}

extern "C" void kernel_launch(void* const* d_in, const int* in_sizes, int n_in,
                              void* d_out, int out_size, void* d_ws, size_t ws_size,
                              hipStream_t stream) {
  const float* x  = (const float*)d_in[0];  // (B, C, T)
  const float* g  = (const float*)d_in[1];  // (B, 1, T)
  const float* Wa = (const float*)d_in[2];  // (1, C, 1)
  const float* Wb = (const float*)d_in[3];  // (1, C, 1)
  const float* Wo = (const float*)d_in[4];  // (C, 1, 1)
  const float* Bo = (const float*)d_in[5];  // (C,)
  float* out = (float*)d_out;

  constexpr int BT = BB * TT;
  float* ws   = (float*)d_ws;
  float* sa   = ws;               // B*T
  float* sb   = sa + BT;
  float* sb2  = sb + BT;
  float* mean = sb2 + BT;
  float* inv  = mean + BT;        // total ~1.25 MiB

  k_reduce_c<<<BB * 32, 512, 0, stream>>>(x, Wa, Wb, sa, sb, sb2);
  k_scan<<<BB, 1024, 0, stream>>>(g, sa, sb, sb2, mean, inv);
  k_out<<<8192, 256, 0, stream>>>(x, mean, inv, Wo, Bo, out);
}